// Round 4
// baseline (240.218 us; speedup 1.0000x reference)
//
#include <hip/hip_runtime.h>
#include <math.h>

#define BB 8
#define SS 2048
#define DD 512
#define HH 8
#define MM (BB*SS)   // 16384

// scan_h chunking
#define CHK 64    // chunks over t
#define CL  32    // stored steps per chunk (CHK*CL == SS)
#define CW  64    // warm-up steps (contraction ~e^-0.87/step)

// retr fused-EMA chunking
#define RT 32     // stored steps per wave
#define RW 128    // EMA warm-up steps ((1-alpha)^128 negligible)

typedef unsigned short u16;
typedef float f32x4 __attribute__((ext_vector_type(4)));
typedef short s16x8 __attribute__((ext_vector_type(8)));

__device__ __forceinline__ u16 f2bf(float x){
  union { float f; unsigned u; } c; c.f = x;
  unsigned r = c.u + 0x7FFF + ((c.u >> 16) & 1);
  return (u16)(r >> 16);
}
__device__ __forceinline__ float bf2f(u16 x){
  union { unsigned u; float f; } c; c.u = ((unsigned)x) << 16;
  return c.f;
}
__device__ __forceinline__ void gload16(const u16* g, u16* l){
  __builtin_amdgcn_global_load_lds(
      (const __attribute__((address_space(1))) unsigned int*)g,
      (__attribute__((address_space(3))) unsigned int*)l, 16, 0, 0);
}

// ---------------- prep kernels ----------------
__global__ void prep_w1(const float* __restrict__ Wr, const float* __restrict__ Wi,
                        u16* __restrict__ W1){
  int id = blockIdx.x*256 + threadIdx.x;            // 512*1024: W1[n][k]
  if (id >= 512*1024) return;
  int n = id >> 10, k = id & 1023;
  float v = (k < 512) ? (Wr[n*512+k] + Wi[n*512+k])
                      : (Wr[n*512+(k-512)] - Wi[n*512+(k-512)]);
  W1[id] = f2bf(v);
}
__global__ void prep_wq(const float* __restrict__ Wq, u16* __restrict__ O){
  int id = blockIdx.x*256 + threadIdx.x;            // 1536*512, already [N][K]
  if (id >= 1536*512) return;
  O[id] = f2bf(Wq[id]);
}
__global__ void prep_w3(const float* __restrict__ Wor, const float* __restrict__ Woi,
                        u16* __restrict__ W3){
  int id = blockIdx.x*256 + threadIdx.x;            // 1024*512: W3[n][k]
  if (id >= 1024*512) return;
  int n = id >> 9, k = id & 511;
  W3[id] = f2bf((n < 512) ? Wor[n*512+k] : Woi[(n-512)*512+k]);
}
__global__ void prep_misc(const float* __restrict__ br, const float* __restrict__ bi,
                          const float* __restrict__ la, float* __restrict__ bc,
                          float* __restrict__ alph){
  int t = threadIdx.x;
  if (t < 512) bc[t] = br[t] + bi[t];
  if (t < 8)   alph[t] = 1.0f/(1.0f + expf(-la[t]));
}

// ---------------- phase 1: h-recurrence, chunked restart ----------------
__global__ __launch_bounds__(256) void scan_h(const float* __restrict__ w,
                                              const float* __restrict__ bb,
                                              u16* __restrict__ X){
  const int e = blockIdx.x*256 + threadIdx.x;   // 0..4095 = B*D
  const int c = blockIdx.y;                     // chunk
  const int b = e >> 9;
  const int d = e & 511;
  const float PHI_F    = 1.61803398874989484820f;
  const float TWO_PI_F = 6.28318530717958647693f;
  const int tstart = c*CL;
  int t0 = tstart - CW; if (t0 < 0) t0 = 0;
  const int nw = tstart - t0;

  const float* wp = w  + ((size_t)b*SS + t0)*DD + d;
  const float* bp = bb + ((size_t)b*SS + t0)*DD + d;
  float hr = 0.f, hi = 0.f;

  #pragma unroll 8
  for (int i=0;i<nw;i++){
    float wv = wp[(size_t)i*DD];
    float bv = bp[(size_t)i*DD];
    float t  = (float)(t0 + i);
    float tphi = fmodf(t * PHI_F, TWO_PI_F);
    float rwl  = __builtin_amdgcn_rcpf(1.0f + fabsf(wv));
    float theta = (hr + hi)*rwl + 2.0f*bv + 2.0f*tphi;
    hi = __sinf(theta);
    hr = __cosf(theta);
  }
  const float* wq = wp + (size_t)nw*DD;
  const float* bq = bp + (size_t)nw*DD;
  u16* xp = X + ((size_t)(b*SS + tstart))*1024 + d;
  #pragma unroll 8
  for (int i=0;i<CL;i++){
    float wv = wq[(size_t)i*DD];
    float bv = bq[(size_t)i*DD];
    float t  = (float)(tstart + i);
    float tphi = fmodf(t * PHI_F, TWO_PI_F);
    float rwl  = __builtin_amdgcn_rcpf(1.0f + fabsf(wv));
    float theta = (hr + hi)*rwl + 2.0f*bv + 2.0f*tphi;
    hi = __sinf(theta);
    hr = __cosf(theta);
    u16* row = xp + (size_t)i*1024;
    row[0]   = f2bf(hr);
    row[512] = f2bf(hi);
  }
}

// ---------------- bf16 MFMA GEMM: C[M x N] = A[M x K] @ W[N x K]^T ----------------
// 128x128 tile, BK=32, 4 waves, global_load_lds staging with pre-swizzled source.
// LDS slot (row, kg) holds global k-chunk (kg ^ f(row)), f(row)=(row>>1)&3 (involution);
// read side applies the same XOR. EPI: 0 = f32->C0 stride N; 1 = f32 split C0/C1
// stride 512; 2 = bf16->C2 stride N.
__global__ __launch_bounds__(256) void gemm_bf16(const u16* __restrict__ A,
                                                 const u16* __restrict__ W,
                                                 float* __restrict__ C0,
                                                 float* __restrict__ C1,
                                                 u16* __restrict__ C2,
                                                 int N, int K, int EPI){
  __shared__ __align__(16) u16 As[128*32];
  __shared__ __align__(16) u16 Bs[128*32];
  const int tid  = threadIdx.x;
  const int m0   = blockIdx.y * 128;
  const int n0   = blockIdx.x * 128;
  const int wave = tid >> 6;
  const int lane = tid & 63;
  const int wr   = wave >> 1, wc = wave & 1;
  const int l15  = lane & 15;
  const int g    = lane >> 4;

  // global_load_lds mapping: wave w issue j covers rows (w*2+j)*16 .. +15.
  // lane l -> row offset l>>2, slot kg = l&3, source k-chunk kg ^ ((l>>3)&3).
  const int rI   = lane >> 2;
  const int kgs  = (lane & 3) ^ ((lane >> 3) & 3);
  const int row0 = (wave*2+0)*16 + rI;
  const int row1 = (wave*2+1)*16 + rI;
  const u16* Asrc0 = A + (size_t)(m0 + row0) * K + kgs*8;
  const u16* Asrc1 = A + (size_t)(m0 + row1) * K + kgs*8;
  const u16* Bsrc0 = W + (size_t)(n0 + row0) * K + kgs*8;
  const u16* Bsrc1 = W + (size_t)(n0 + row1) * K + kgs*8;
  u16* AL0 = As + (wave*2+0)*512;
  u16* AL1 = As + (wave*2+1)*512;
  u16* BL0 = Bs + (wave*2+0)*512;
  u16* BL1 = Bs + (wave*2+1)*512;

  f32x4 acc[4][4];
  #pragma unroll
  for (int i=0;i<4;i++)
    #pragma unroll
    for (int j=0;j<4;j++) acc[i][j] = (f32x4){0.f,0.f,0.f,0.f};

  for (int k0 = 0; k0 < K; k0 += 32){
    __syncthreads();
    gload16(Asrc0 + k0, AL0);
    gload16(Asrc1 + k0, AL1);
    gload16(Bsrc0 + k0, BL0);
    gload16(Bsrc1 + k0, BL1);
    __syncthreads();   // drains vmcnt -> LDS tile complete
    s16x8 af[4], bf[4];
    #pragma unroll
    for (int s=0;s<4;s++){
      int rA = wr*64 + s*16 + l15;
      af[s] = *(const s16x8*)&As[rA*32 + ((g ^ ((rA>>1)&3))*8)];
      int rB = wc*64 + s*16 + l15;
      bf[s] = *(const s16x8*)&Bs[rB*32 + ((g ^ ((rB>>1)&3))*8)];
    }
    #pragma unroll
    for (int mi=0;mi<4;mi++)
      #pragma unroll
      for (int ni=0;ni<4;ni++)
        acc[mi][ni] = __builtin_amdgcn_mfma_f32_16x16x32_bf16(af[mi], bf[ni], acc[mi][ni], 0, 0, 0);
  }

  #pragma unroll
  for (int mi=0;mi<4;mi++){
    #pragma unroll
    for (int j=0;j<4;j++){
      int r = m0 + wr*64 + mi*16 + g*4 + j;
      #pragma unroll
      for (int ni=0;ni<4;ni++){
        int col = n0 + wc*64 + ni*16 + l15;
        float v = acc[mi][ni][j];
        if (EPI == 0){
          C0[(size_t)r*N + col] = v;
        } else if (EPI == 1){
          if (col < 512) C0[(size_t)r*512 + col]       = v;
          else           C1[(size_t)r*512 + (col-512)] = v;
        } else {
          C2[(size_t)r*N + col] = f2bf(v);
        }
      }
    }
  }
}

// ---------------- LayerNorm: xc = LN(y + bc)*g + b  (f32 in, bf16 out) ----------------
__global__ __launch_bounds__(256) void ln_kernel(const float* __restrict__ y,
                                                 const float* __restrict__ bc,
                                                 const float* __restrict__ g,
                                                 const float* __restrict__ bb,
                                                 u16* __restrict__ xc){
  const int row  = blockIdx.x*4 + (threadIdx.x >> 6);
  const int lane = threadIdx.x & 63;
  const float* yr = y + (size_t)row*512;
  float4 v0 = ((const float4*)yr)[lane];
  float4 v1 = ((const float4*)yr)[lane+64];
  float4 c0 = ((const float4*)bc)[lane];
  float4 c1 = ((const float4*)bc)[lane+64];
  v0.x+=c0.x; v0.y+=c0.y; v0.z+=c0.z; v0.w+=c0.w;
  v1.x+=c1.x; v1.y+=c1.y; v1.z+=c1.z; v1.w+=c1.w;
  float s  = v0.x+v0.y+v0.z+v0.w + v1.x+v1.y+v1.z+v1.w;
  float s2 = v0.x*v0.x+v0.y*v0.y+v0.z*v0.z+v0.w*v0.w
           + v1.x*v1.x+v1.y*v1.y+v1.z*v1.z+v1.w*v1.w;
  #pragma unroll
  for (int off=32; off>0; off>>=1){ s += __shfl_xor(s, off); s2 += __shfl_xor(s2, off); }
  float mean = s * (1.0f/512.0f);
  float var  = s2 * (1.0f/512.0f) - mean*mean;
  float rstd = rsqrtf(var + 1e-5f);
  float4 g0 = ((const float4*)g)[lane],  g1 = ((const float4*)g)[lane+64];
  float4 b0 = ((const float4*)bb)[lane], b1 = ((const float4*)bb)[lane+64];
  ushort4 o0, o1;
  o0.x = f2bf((v0.x-mean)*rstd*g0.x + b0.x);
  o0.y = f2bf((v0.y-mean)*rstd*g0.y + b0.y);
  o0.z = f2bf((v0.z-mean)*rstd*g0.z + b0.z);
  o0.w = f2bf((v0.w-mean)*rstd*g0.w + b0.w);
  o1.x = f2bf((v1.x-mean)*rstd*g1.x + b1.x);
  o1.y = f2bf((v1.y-mean)*rstd*g1.y + b1.y);
  o1.z = f2bf((v1.z-mean)*rstd*g1.z + b1.z);
  o1.w = f2bf((v1.w-mean)*rstd*g1.w + b1.w);
  ushort4* xr = (ushort4*)(xc + (size_t)row*512);
  xr[lane]    = o0;
  xr[lane+64] = o1;
}

// ---------------- fused EMA + gate + retr ----------------
// wave = (b, h, chunk): 64 lanes = head dims. Truncated EMA warm-up RW steps,
// then RT stored steps: gate = sigmoid(sum_d q*k / 8) via wave shfl-reduce.
__global__ __launch_bounds__(256) void retr_fused(const u16* __restrict__ qkv,
                                                  const float* __restrict__ alph,
                                                  u16* __restrict__ retr){
  const int wid  = blockIdx.x*4 + (threadIdx.x >> 6);   // 0..4095
  const int lane = threadIdx.x & 63;
  const int c = wid & 63;
  const int h = (wid >> 6) & 7;
  const int b = wid >> 9;
  const float a  = alph[h];
  const float om = 1.0f - a;
  const int d  = h*64 + lane;
  const int t0 = c*RT;
  int w0 = t0 - RW; if (w0 < 0) w0 = 0;
  const int nw = t0 - w0;

  const u16* vp = qkv + ((size_t)(b*SS + w0))*1536 + 1024 + d;
  float vs = 0.f;
  #pragma unroll 8
  for (int i=0;i<nw;i++){
    vs = fmaf(a, bf2f(vp[(size_t)i*1536]), om*vs);
  }
  const u16* qp = qkv + ((size_t)(b*SS + t0))*1536 + d;
  u16* op = retr + ((size_t)(b*SS + t0))*512 + d;
  #pragma unroll 4
  for (int i=0;i<RT;i++){
    float q  = bf2f(qp[(size_t)i*1536]);
    float kk = bf2f(qp[(size_t)i*1536 + 512]);
    float v  = bf2f(qp[(size_t)i*1536 + 1024]);
    vs = fmaf(a, v, om*vs);
    float p = q*kk;
    #pragma unroll
    for (int off=32; off>0; off>>=1) p += __shfl_xor(p, off);
    float gate = 1.0f/(1.0f + __expf(-p*0.125f));
    op[(size_t)i*512] = f2bf(gate * vs);
  }
}

extern "C" void kernel_launch(void* const* d_in, const int* in_sizes, int n_in,
                              void* d_out, int out_size, void* d_ws, size_t ws_size,
                              hipStream_t stream) {
  const float* w    = (const float*)d_in[0];
  const float* b    = (const float*)d_in[1];
  const float* ipWr = (const float*)d_in[2];
  const float* ipWi = (const float*)d_in[3];
  const float* ipbr = (const float*)d_in[4];
  const float* ipbi = (const float*)d_in[5];
  const float* lng  = (const float*)d_in[6];
  const float* lnb  = (const float*)d_in[7];
  const float* Wqkv = (const float*)d_in[8];
  const float* la   = (const float*)d_in[9];
  const float* opWr = (const float*)d_in[10];
  const float* opWi = (const float*)d_in[11];
  float* out0 = (float*)d_out;                    // (B,S,D) real part
  float* out1 = out0 + (size_t)MM*DD;             // imag part

  char* base = (char*)d_ws;
  u16*   W1   = (u16*)  (base + 0);               // 512x1024 bf16
  u16*   Wq   = (u16*)  (base + 1048576);         // 1536x512 bf16
  u16*   W3   = (u16*)  (base + 2621440);         // 1024x512 bf16
  float* bc   = (float*)(base + 3670016);         // 512 f32
  float* alph = (float*)(base + 3672064);         // 8 f32
  u16*   X    = (u16*)  (base + 3672096);         // M*1024 bf16 [hr2|hi2]
  float* y    = (float*)(base + 37226528);        // M*512 f32
  u16*   xc   = (u16*)  (base + 70780960);        // M*512 bf16
  u16*   qkv  = (u16*)  (base + 87558176);        // M*1536 bf16
  u16*   retr = X;                                // alias: X dead after GEMM1

  prep_w1 <<<2048,256,0,stream>>>(ipWr, ipWi, W1);
  prep_wq <<<3072,256,0,stream>>>(Wqkv, Wq);
  prep_w3 <<<2048,256,0,stream>>>(opWr, opWi, W3);
  prep_misc<<<1,512,0,stream>>>(ipbr, ipbi, la, bc, alph);

  scan_h<<<dim3(16,CHK),256,0,stream>>>(w, b, X);

  gemm_bf16<<<dim3(4,128),256,0,stream>>>(X, W1, y, nullptr, nullptr, 512, 1024, 0);
  ln_kernel<<<4096,256,0,stream>>>(y, bc, lng, lnb, xc);
  gemm_bf16<<<dim3(12,128),256,0,stream>>>(xc, Wq, nullptr, nullptr, qkv, 1536, 512, 2);

  retr_fused<<<1024,256,0,stream>>>(qkv, alph, retr);

  gemm_bf16<<<dim3(8,128),256,0,stream>>>(retr, W3, out0, out1, nullptr, 1024, 512, 1);
}

// Round 5
// 231.202 us; speedup vs baseline: 1.0390x; 1.0390x over previous
//
#include <hip/hip_runtime.h>
#include <math.h>

#define BB 8
#define SS 2048
#define DD 512
#define HH 8
#define MM (BB*SS)   // 16384

// scan_h chunking
#define CHK 128   // chunks over t
#define CL  16    // stored steps per chunk (CHK*CL == SS)
#define CW  64    // warm-up steps (contraction ~e^-0.87/step)

// retr fused-EMA chunking
#define RT 32     // stored steps per wave
#define RW 128    // EMA warm-up steps ((1-alpha)^128 negligible)

typedef unsigned short u16;
typedef float f32x4 __attribute__((ext_vector_type(4)));
typedef short s16x8 __attribute__((ext_vector_type(8)));

__device__ __forceinline__ u16 f2bf(float x){
  union { float f; unsigned u; } c; c.f = x;
  unsigned r = c.u + 0x7FFF + ((c.u >> 16) & 1);
  return (u16)(r >> 16);
}
__device__ __forceinline__ float bf2f(u16 x){
  union { unsigned u; float f; } c; c.u = ((unsigned)x) << 16;
  return c.f;
}
__device__ __forceinline__ void gload16(const u16* g, u16* l){
  __builtin_amdgcn_global_load_lds(
      (const __attribute__((address_space(1))) unsigned int*)g,
      (__attribute__((address_space(3))) unsigned int*)l, 16, 0, 0);
}

// ---------------- prep kernels ----------------
__global__ void prep_w1(const float* __restrict__ Wr, const float* __restrict__ Wi,
                        u16* __restrict__ W1){
  int id = blockIdx.x*256 + threadIdx.x;            // 512*1024: W1[n][k]
  if (id >= 512*1024) return;
  int n = id >> 10, k = id & 1023;
  float v = (k < 512) ? (Wr[n*512+k] + Wi[n*512+k])
                      : (Wr[n*512+(k-512)] - Wi[n*512+(k-512)]);
  W1[id] = f2bf(v);
}
__global__ void prep_wq(const float* __restrict__ Wq, u16* __restrict__ O){
  int id = blockIdx.x*256 + threadIdx.x;            // 1536*512, already [N][K]
  if (id >= 1536*512) return;
  O[id] = f2bf(Wq[id]);
}
__global__ void prep_w3(const float* __restrict__ Wor, const float* __restrict__ Woi,
                        u16* __restrict__ W3){
  int id = blockIdx.x*256 + threadIdx.x;            // 1024*512: W3[n][k]
  if (id >= 1024*512) return;
  int n = id >> 9, k = id & 511;
  W3[id] = f2bf((n < 512) ? Wor[n*512+k] : Woi[(n-512)*512+k]);
}
__global__ void prep_misc(const float* __restrict__ br, const float* __restrict__ bi,
                          const float* __restrict__ la, float* __restrict__ bc,
                          float* __restrict__ alph){
  int t = threadIdx.x;
  if (t < 512) bc[t] = br[t] + bi[t];
  if (t < 8)   alph[t] = 1.0f/(1.0f + expf(-la[t]));
}

// ---------------- phase 1: h-recurrence, chunked restart ----------------
__global__ __launch_bounds__(256) void scan_h(const float* __restrict__ w,
                                              const float* __restrict__ bb,
                                              u16* __restrict__ X){
  const int e = blockIdx.x*256 + threadIdx.x;   // 0..4095 = B*D
  const int c = blockIdx.y;                     // chunk
  const int b = e >> 9;
  const int d = e & 511;
  const float PHI_F    = 1.61803398874989484820f;
  const float TWO_PI_F = 6.28318530717958647693f;
  const int tstart = c*CL;
  int t0 = tstart - CW; if (t0 < 0) t0 = 0;
  const int nw = tstart - t0;

  const float* wp = w  + ((size_t)b*SS + t0)*DD + d;
  const float* bp = bb + ((size_t)b*SS + t0)*DD + d;
  float hr = 0.f, hi = 0.f;

  #pragma unroll 8
  for (int i=0;i<nw;i++){
    float wv = wp[(size_t)i*DD];
    float bv = bp[(size_t)i*DD];
    float t  = (float)(t0 + i);
    float tphi = fmodf(t * PHI_F, TWO_PI_F);
    float rwl  = __builtin_amdgcn_rcpf(1.0f + fabsf(wv));
    float theta = (hr + hi)*rwl + 2.0f*bv + 2.0f*tphi;
    hi = __sinf(theta);
    hr = __cosf(theta);
  }
  const float* wq = wp + (size_t)nw*DD;
  const float* bq = bp + (size_t)nw*DD;
  u16* xp = X + ((size_t)(b*SS + tstart))*1024 + d;
  #pragma unroll 8
  for (int i=0;i<CL;i++){
    float wv = wq[(size_t)i*DD];
    float bv = bq[(size_t)i*DD];
    float t  = (float)(tstart + i);
    float tphi = fmodf(t * PHI_F, TWO_PI_F);
    float rwl  = __builtin_amdgcn_rcpf(1.0f + fabsf(wv));
    float theta = (hr + hi)*rwl + 2.0f*bv + 2.0f*tphi;
    hi = __sinf(theta);
    hr = __cosf(theta);
    u16* row = xp + (size_t)i*1024;
    row[0]   = f2bf(hr);
    row[512] = f2bf(hi);
  }
}

// ---------------- bf16 MFMA GEMM: C[M x N] = A[M x K] @ W[N x K]^T ----------------
// 128x128 tile, BK=32, 4 waves, 2-phase double-buffered global_load_lds staging.
// Bijective XCD swizzle on block id (all grids divisible by 8).
// LDS slot (row, kg) holds global k-chunk (kg ^ ((row>>1)&3)); read applies same XOR.
// EPI: 0 = f32->C0 stride N; 1 = f32 split C0/C1 stride 512; 2 = bf16->C2 stride N.
__global__ __launch_bounds__(256) void gemm_bf16(const u16* __restrict__ A,
                                                 const u16* __restrict__ W,
                                                 float* __restrict__ C0,
                                                 float* __restrict__ C1,
                                                 u16* __restrict__ C2,
                                                 int N, int K, int EPI){
  __shared__ __align__(16) u16 As[2][128*32];
  __shared__ __align__(16) u16 Bs[2][128*32];
  const int tid  = threadIdx.x;
  // XCD-aware bijective swizzle (nwg % 8 == 0 for all our grids)
  const int nwgx = gridDim.x;
  const int nwg  = nwgx * gridDim.y;
  const int lin  = blockIdx.y * nwgx + blockIdx.x;
  const int qq   = nwg >> 3;
  const int logi = (lin & 7) * qq + (lin >> 3);
  const int m0   = (logi / nwgx) * 128;
  const int n0   = (logi % nwgx) * 128;

  const int wave = tid >> 6;
  const int lane = tid & 63;
  const int wr   = wave >> 1, wc = wave & 1;
  const int l15  = lane & 15;
  const int g    = lane >> 4;

  // staging: wave w issue j covers rows (w*2+j)*16..+15; lane l -> row l>>2,
  // LDS slot kg = l&3, source k-chunk kg ^ ((l>>3)&3)  (involution).
  const int rI   = lane >> 2;
  const int kgs  = (lane & 3) ^ ((lane >> 3) & 3);
  const int row0 = (wave*2+0)*16 + rI;
  const int row1 = (wave*2+1)*16 + rI;
  const u16* Asrc0 = A + (size_t)(m0 + row0) * K + kgs*8;
  const u16* Asrc1 = A + (size_t)(m0 + row1) * K + kgs*8;
  const u16* Bsrc0 = W + (size_t)(n0 + row0) * K + kgs*8;
  const u16* Bsrc1 = W + (size_t)(n0 + row1) * K + kgs*8;
  const int ld0 = (wave*2+0)*512;
  const int ld1 = (wave*2+1)*512;

  f32x4 acc[4][4];
  #pragma unroll
  for (int i=0;i<4;i++)
    #pragma unroll
    for (int j=0;j<4;j++) acc[i][j] = (f32x4){0.f,0.f,0.f,0.f};

#define STAGE(buf, koff) do {                      \
    gload16(Asrc0 + (koff), &As[buf][ld0]);        \
    gload16(Asrc1 + (koff), &As[buf][ld1]);        \
    gload16(Bsrc0 + (koff), &Bs[buf][ld0]);        \
    gload16(Bsrc1 + (koff), &Bs[buf][ld1]);        \
  } while(0)

#define COMPUTE(buf) do {                                            \
    s16x8 af[4], bf[4];                                              \
    _Pragma("unroll")                                                \
    for (int s=0;s<4;s++){                                           \
      int rA = wr*64 + s*16 + l15;                                   \
      af[s] = *(const s16x8*)&As[buf][rA*32 + ((g ^ ((rA>>1)&3))*8)];\
      int rB = wc*64 + s*16 + l15;                                   \
      bf[s] = *(const s16x8*)&Bs[buf][rB*32 + ((g ^ ((rB>>1)&3))*8)];\
    }                                                                \
    _Pragma("unroll")                                                \
    for (int mi=0;mi<4;mi++)                                         \
      _Pragma("unroll")                                              \
      for (int ni=0;ni<4;ni++)                                       \
        acc[mi][ni] = __builtin_amdgcn_mfma_f32_16x16x32_bf16(af[mi], bf[ni], acc[mi][ni], 0, 0, 0); \
  } while(0)

  STAGE(0, 0);
  __syncthreads();          // drain vmcnt(0): buf0 ready
  int cur = 0;
  for (int k0 = 32; k0 < K; k0 += 32){
    STAGE(cur^1, k0);       // loads in flight during compute
    COMPUTE(cur);
    __syncthreads();        // drains vmcnt+lgkmcnt: buf^1 ready, buf reads done
    cur ^= 1;
  }
  COMPUTE(cur);

#undef STAGE
#undef COMPUTE

  #pragma unroll
  for (int mi=0;mi<4;mi++){
    #pragma unroll
    for (int j=0;j<4;j++){
      int r = m0 + wr*64 + mi*16 + g*4 + j;
      #pragma unroll
      for (int ni=0;ni<4;ni++){
        int col = n0 + wc*64 + ni*16 + l15;
        float v = acc[mi][ni][j];
        if (EPI == 0){
          C0[(size_t)r*N + col] = v;
        } else if (EPI == 1){
          if (col < 512) C0[(size_t)r*512 + col]       = v;
          else           C1[(size_t)r*512 + (col-512)] = v;
        } else {
          C2[(size_t)r*N + col] = f2bf(v);
        }
      }
    }
  }
}

// ---------------- LayerNorm: xc = LN(y + bc)*g + b  (bf16 in, bf16 out) ----------------
__global__ __launch_bounds__(256) void ln_kernel(const u16* __restrict__ y,
                                                 const float* __restrict__ bc,
                                                 const float* __restrict__ g,
                                                 const float* __restrict__ bb,
                                                 u16* __restrict__ xc){
  const int row  = blockIdx.x*4 + (threadIdx.x >> 6);
  const int lane = threadIdx.x & 63;
  s16x8 v = *(const s16x8*)(y + (size_t)row*512 + lane*8);
  float4 c0 = ((const float4*)bc)[lane*2];
  float4 c1 = ((const float4*)bc)[lane*2+1];
  float f[8];
  f[0] = bf2f((u16)v[0]) + c0.x; f[1] = bf2f((u16)v[1]) + c0.y;
  f[2] = bf2f((u16)v[2]) + c0.z; f[3] = bf2f((u16)v[3]) + c0.w;
  f[4] = bf2f((u16)v[4]) + c1.x; f[5] = bf2f((u16)v[5]) + c1.y;
  f[6] = bf2f((u16)v[6]) + c1.z; f[7] = bf2f((u16)v[7]) + c1.w;
  float s = 0.f, s2 = 0.f;
  #pragma unroll
  for (int i=0;i<8;i++){ s += f[i]; s2 = fmaf(f[i], f[i], s2); }
  #pragma unroll
  for (int off=32; off>0; off>>=1){ s += __shfl_xor(s, off); s2 += __shfl_xor(s2, off); }
  float mean = s * (1.0f/512.0f);
  float var  = s2 * (1.0f/512.0f) - mean*mean;
  float rstd = rsqrtf(var + 1e-5f);
  float4 g0 = ((const float4*)g)[lane*2],  g1 = ((const float4*)g)[lane*2+1];
  float4 b0 = ((const float4*)bb)[lane*2], b1 = ((const float4*)bb)[lane*2+1];
  s16x8 o;
  o[0] = (short)f2bf((f[0]-mean)*rstd*g0.x + b0.x);
  o[1] = (short)f2bf((f[1]-mean)*rstd*g0.y + b0.y);
  o[2] = (short)f2bf((f[2]-mean)*rstd*g0.z + b0.z);
  o[3] = (short)f2bf((f[3]-mean)*rstd*g0.w + b0.w);
  o[4] = (short)f2bf((f[4]-mean)*rstd*g1.x + b1.x);
  o[5] = (short)f2bf((f[5]-mean)*rstd*g1.y + b1.y);
  o[6] = (short)f2bf((f[6]-mean)*rstd*g1.z + b1.z);
  o[7] = (short)f2bf((f[7]-mean)*rstd*g1.w + b1.w);
  *(s16x8*)(xc + (size_t)row*512 + lane*8) = o;
}

// ---------------- fused EMA + gate + retr ----------------
__global__ __launch_bounds__(256) void retr_fused(const u16* __restrict__ qkv,
                                                  const float* __restrict__ alph,
                                                  u16* __restrict__ retr){
  const int wid  = blockIdx.x*4 + (threadIdx.x >> 6);   // 0..4095
  const int lane = threadIdx.x & 63;
  const int c = wid & 63;
  const int h = (wid >> 6) & 7;
  const int b = wid >> 9;
  const float a  = alph[h];
  const float om = 1.0f - a;
  const int d  = h*64 + lane;
  const int t0 = c*RT;
  int w0 = t0 - RW; if (w0 < 0) w0 = 0;
  const int nw = t0 - w0;

  const u16* vp = qkv + ((size_t)(b*SS + w0))*1536 + 1024 + d;
  float vs = 0.f;
  #pragma unroll 8
  for (int i=0;i<nw;i++){
    vs = fmaf(a, bf2f(vp[(size_t)i*1536]), om*vs);
  }
  const u16* qp = qkv + ((size_t)(b*SS + t0))*1536 + d;
  u16* op = retr + ((size_t)(b*SS + t0))*512 + d;
  #pragma unroll 4
  for (int i=0;i<RT;i++){
    float q  = bf2f(qp[(size_t)i*1536]);
    float kk = bf2f(qp[(size_t)i*1536 + 512]);
    float v  = bf2f(qp[(size_t)i*1536 + 1024]);
    vs = fmaf(a, v, om*vs);
    float p = q*kk;
    #pragma unroll
    for (int off=32; off>0; off>>=1) p += __shfl_xor(p, off);
    float gate = 1.0f/(1.0f + __expf(-p*0.125f));
    op[(size_t)i*512] = f2bf(gate * vs);
  }
}

extern "C" void kernel_launch(void* const* d_in, const int* in_sizes, int n_in,
                              void* d_out, int out_size, void* d_ws, size_t ws_size,
                              hipStream_t stream) {
  const float* w    = (const float*)d_in[0];
  const float* b    = (const float*)d_in[1];
  const float* ipWr = (const float*)d_in[2];
  const float* ipWi = (const float*)d_in[3];
  const float* ipbr = (const float*)d_in[4];
  const float* ipbi = (const float*)d_in[5];
  const float* lng  = (const float*)d_in[6];
  const float* lnb  = (const float*)d_in[7];
  const float* Wqkv = (const float*)d_in[8];
  const float* la   = (const float*)d_in[9];
  const float* opWr = (const float*)d_in[10];
  const float* opWi = (const float*)d_in[11];
  float* out0 = (float*)d_out;                    // (B,S,D) real part
  float* out1 = out0 + (size_t)MM*DD;             // imag part

  char* base = (char*)d_ws;
  u16*   W1   = (u16*)  (base + 0);               // 512x1024 bf16
  u16*   Wq   = (u16*)  (base + 1048576);         // 1536x512 bf16
  u16*   W3   = (u16*)  (base + 2621440);         // 1024x512 bf16
  float* bc   = (float*)(base + 3670016);         // 512 f32
  float* alph = (float*)(base + 3672064);         // 8 f32
  u16*   X    = (u16*)  (base + 3672096);         // M*1024 bf16 [hr2|hi2]
  u16*   y    = (u16*)  (base + 37226528);        // M*512 bf16
  u16*   xc   = (u16*)  (base + 54003744);        // M*512 bf16
  u16*   qkv  = (u16*)  (base + 70780960);        // M*1536 bf16
  u16*   retr = X;                                // alias: X dead after GEMM1

  prep_w1 <<<2048,256,0,stream>>>(ipWr, ipWi, W1);
  prep_wq <<<3072,256,0,stream>>>(Wqkv, Wq);
  prep_w3 <<<2048,256,0,stream>>>(opWr, opWi, W3);
  prep_misc<<<1,512,0,stream>>>(ipbr, ipbi, la, bc, alph);

  scan_h<<<dim3(16,CHK),256,0,stream>>>(w, b, X);

  gemm_bf16<<<dim3(4,128),256,0,stream>>>(X, W1, nullptr, nullptr, y, 512, 1024, 2);
  ln_kernel<<<4096,256,0,stream>>>(y, bc, lng, lnb, xc);
  gemm_bf16<<<dim3(12,128),256,0,stream>>>(xc, Wq, nullptr, nullptr, qkv, 1536, 512, 2);

  retr_fused<<<1024,256,0,stream>>>(qkv, alph, retr);

  gemm_bf16<<<dim3(8,128),256,0,stream>>>(retr, W3, out0, out1, nullptr, 1024, 512, 1);
}

// Round 6
// 181.150 us; speedup vs baseline: 1.3261x; 1.2763x over previous
//
#include <hip/hip_runtime.h>
#include <math.h>

#define BB 8
#define SS 2048
#define DD 512
#define HH 8
#define MM (BB*SS)   // 16384

// scan_h chunking
#define CHK 64    // chunks over t
#define CL  32    // stored steps per chunk (CHK*CL == SS)
#define CW  64    // warm-up steps (contraction ~e^-0.87/step)

// retr fused-EMA chunking
#define RT 32     // stored steps per wave
#define RW 128    // EMA warm-up steps ((1-alpha)^128 negligible)

typedef unsigned short u16;
typedef unsigned int   u32;
typedef float f32x4 __attribute__((ext_vector_type(4)));
typedef short s16x8 __attribute__((ext_vector_type(8)));

__device__ __forceinline__ u16 f2bf(float x){
  union { float f; unsigned u; } c; c.f = x;
  unsigned r = c.u + 0x7FFF + ((c.u >> 16) & 1);
  return (u16)(r >> 16);
}
__device__ __forceinline__ float bf2f(u16 x){
  union { unsigned u; float f; } c; c.u = ((unsigned)x) << 16;
  return c.f;
}
__device__ __forceinline__ void gload16(const u16* g, u16* l){
  __builtin_amdgcn_global_load_lds(
      (const __attribute__((address_space(1))) unsigned int*)g,
      (__attribute__((address_space(3))) unsigned int*)l, 16, 0, 0);
}

// ---------------- prep kernels ----------------
// W1[n][2d]   = Wr[n][d] + Wi[n][d]   (pairs with hr2 = cos)
// W1[n][2d+1] = Wr[n][d] - Wi[n][d]   (pairs with hi2 = sin)
__global__ void prep_w1(const float* __restrict__ Wr, const float* __restrict__ Wi,
                        u16* __restrict__ W1){
  int id = blockIdx.x*256 + threadIdx.x;            // 512*1024
  if (id >= 512*1024) return;
  int n = id >> 10, k = id & 1023;
  int d = k >> 1;
  float v = (k & 1) ? (Wr[n*512+d] - Wi[n*512+d])
                    : (Wr[n*512+d] + Wi[n*512+d]);
  W1[id] = f2bf(v);
}
__global__ void prep_wq(const float* __restrict__ Wq, u16* __restrict__ O){
  int id = blockIdx.x*256 + threadIdx.x;            // 1536*512, already [N][K]
  if (id >= 1536*512) return;
  O[id] = f2bf(Wq[id]);
}
__global__ void prep_w3(const float* __restrict__ Wor, const float* __restrict__ Woi,
                        u16* __restrict__ W3){
  int id = blockIdx.x*256 + threadIdx.x;            // 1024*512: W3[n][k]
  if (id >= 1024*512) return;
  int n = id >> 9, k = id & 511;
  W3[id] = f2bf((n < 512) ? Wor[n*512+k] : Woi[(n-512)*512+k]);
}
__global__ void prep_misc(const float* __restrict__ br, const float* __restrict__ bi,
                          const float* __restrict__ la, float* __restrict__ bc,
                          float* __restrict__ alph){
  int t = threadIdx.x;
  if (t < 512) bc[t] = br[t] + bi[t];
  if (t < 8)   alph[t] = 1.0f/(1.0f + expf(-la[t]));
}
__global__ void prep_tphi(float* __restrict__ tphi2){
  int t = blockIdx.x*256 + threadIdx.x;             // 2048
  if (t >= SS) return;
  const float PHI_F    = 1.61803398874989484820f;
  const float TWO_PI_F = 6.28318530717958647693f;
  tphi2[t] = 2.0f * fmodf((float)t * PHI_F, TWO_PI_F);
}

// ---------------- phase 1: h-recurrence, chunked restart ----------------
// X32[row][d] = pack(bf16(cos theta), bf16(sin theta)), row = b*S+t.
// Warm-up tracks ss = sin(theta + pi/4) only:  cos+sin = sqrt2*sin(theta+pi/4).
__global__ __launch_bounds__(256) void scan_h(const float* __restrict__ w,
                                              const float* __restrict__ bb,
                                              const float* __restrict__ tphi2,
                                              u32* __restrict__ X32){
  const int e = blockIdx.x*256 + threadIdx.x;   // 0..4095 = B*D
  const int c = blockIdx.y;                     // chunk
  const int b = e >> 9;
  const int d = e & 511;
  const float SQRT2 = 1.41421356237309504880f;
  const float PI_4  = 0.78539816339744830962f;
  const int tstart = c*CL;
  int t0 = tstart - CW; if (t0 < 0) t0 = 0;
  const int nw = tstart - t0;

  const float* wp = w  + ((size_t)b*SS + t0)*DD + d;
  const float* bp = bb + ((size_t)b*SS + t0)*DD + d;
  const float* tp = tphi2 + t0;

  float ss = 0.f;   // sin(theta + pi/4); hr+hi = sqrt2*ss
  #pragma unroll 8
  for (int i=0;i<nw;i++){
    float wv = wp[(size_t)i*DD];
    float bv = bp[(size_t)i*DD];
    float rwl2 = SQRT2 * __builtin_amdgcn_rcpf(1.0f + fabsf(wv));
    float cw   = fmaf(2.0f, bv, tp[i]) + PI_4;
    ss = __sinf(fmaf(ss, rwl2, cw));
  }
  float hs = SQRT2 * ss;   // = hr + hi

  const float* wq = wp + (size_t)nw*DD;
  const float* bq = bp + (size_t)nw*DD;
  u32* xp = X32 + (size_t)(b*SS + tstart)*512 + d;
  #pragma unroll 8
  for (int i=0;i<CL;i++){
    float wv = wq[(size_t)i*DD];
    float bv = bq[(size_t)i*DD];
    float rwl = __builtin_amdgcn_rcpf(1.0f + fabsf(wv));
    float cc  = fmaf(2.0f, bv, tp[nw+i]);
    float theta = fmaf(hs, rwl, cc);
    float sn = __sinf(theta);
    float cs = __cosf(theta);
    hs = cs + sn;
    xp[(size_t)i*512] = (u32)f2bf(cs) | ((u32)f2bf(sn) << 16);
  }
}

// ---------------- bf16 MFMA GEMM: C[M x N] = A[M x K] @ W[N x K]^T ----------------
// 128x128 tile, BK=32, 4 waves, 2-phase double-buffered global_load_lds staging.
// Bijective XCD swizzle; LDS slot (row,kg) holds k-chunk kg^((row>>1)&3).
// EPI: 1 = f32 split C0/C1 stride 512; 2 = bf16->C2 stride N. TAG: profiling id.
template<int TAG, int EPI>
__global__ __launch_bounds__(256) void gemm_bf16(const u16* __restrict__ A,
                                                 const u16* __restrict__ W,
                                                 float* __restrict__ C0,
                                                 float* __restrict__ C1,
                                                 u16* __restrict__ C2,
                                                 int N, int K){
  __shared__ __align__(16) u16 As[2][128*32];
  __shared__ __align__(16) u16 Bs[2][128*32];
  const int tid  = threadIdx.x;
  const int nwgx = gridDim.x;
  const int nwg  = nwgx * gridDim.y;
  const int lin  = blockIdx.y * nwgx + blockIdx.x;
  const int qq   = nwg >> 3;
  const int logi = (lin & 7) * qq + (lin >> 3);
  const int m0   = (logi / nwgx) * 128;
  const int n0   = (logi % nwgx) * 128;

  const int wave = tid >> 6;
  const int lane = tid & 63;
  const int wr   = wave >> 1, wc = wave & 1;
  const int l15  = lane & 15;
  const int g    = lane >> 4;

  const int rI   = lane >> 2;
  const int kgs  = (lane & 3) ^ ((lane >> 3) & 3);
  const int row0 = (wave*2+0)*16 + rI;
  const int row1 = (wave*2+1)*16 + rI;
  const u16* Asrc0 = A + (size_t)(m0 + row0) * K + kgs*8;
  const u16* Asrc1 = A + (size_t)(m0 + row1) * K + kgs*8;
  const u16* Bsrc0 = W + (size_t)(n0 + row0) * K + kgs*8;
  const u16* Bsrc1 = W + (size_t)(n0 + row1) * K + kgs*8;
  const int ld0 = (wave*2+0)*512;
  const int ld1 = (wave*2+1)*512;

  f32x4 acc[4][4];
  #pragma unroll
  for (int i=0;i<4;i++)
    #pragma unroll
    for (int j=0;j<4;j++) acc[i][j] = (f32x4){0.f,0.f,0.f,0.f};

#define STAGE(buf, koff) do {                      \
    gload16(Asrc0 + (koff), &As[buf][ld0]);        \
    gload16(Asrc1 + (koff), &As[buf][ld1]);        \
    gload16(Bsrc0 + (koff), &Bs[buf][ld0]);        \
    gload16(Bsrc1 + (koff), &Bs[buf][ld1]);        \
  } while(0)

#define COMPUTE(buf) do {                                            \
    s16x8 af[4], bf[4];                                              \
    _Pragma("unroll")                                                \
    for (int s=0;s<4;s++){                                           \
      int rA = wr*64 + s*16 + l15;                                   \
      af[s] = *(const s16x8*)&As[buf][rA*32 + ((g ^ ((rA>>1)&3))*8)];\
      int rB = wc*64 + s*16 + l15;                                   \
      bf[s] = *(const s16x8*)&Bs[buf][rB*32 + ((g ^ ((rB>>1)&3))*8)];\
    }                                                                \
    _Pragma("unroll")                                                \
    for (int mi=0;mi<4;mi++)                                         \
      _Pragma("unroll")                                              \
      for (int ni=0;ni<4;ni++)                                       \
        acc[mi][ni] = __builtin_amdgcn_mfma_f32_16x16x32_bf16(af[mi], bf[ni], acc[mi][ni], 0, 0, 0); \
  } while(0)

  STAGE(0, 0);
  __syncthreads();
  int cur = 0;
  for (int k0 = 32; k0 < K; k0 += 32){
    STAGE(cur^1, k0);
    COMPUTE(cur);
    __syncthreads();
    cur ^= 1;
  }
  COMPUTE(cur);

#undef STAGE
#undef COMPUTE

  #pragma unroll
  for (int mi=0;mi<4;mi++){
    #pragma unroll
    for (int j=0;j<4;j++){
      int r = m0 + wr*64 + mi*16 + g*4 + j;
      #pragma unroll
      for (int ni=0;ni<4;ni++){
        int col = n0 + wc*64 + ni*16 + l15;
        float v = acc[mi][ni][j];
        if (EPI == 1){
          if (col < 512) C0[(size_t)r*512 + col]       = v;
          else           C1[(size_t)r*512 + (col-512)] = v;
        } else {
          C2[(size_t)r*N + col] = f2bf(v);
        }
      }
    }
  }
}

// ---------------- LayerNorm: xc = LN(y + bc)*g + b  (bf16 in, bf16 out) ----------------
__global__ __launch_bounds__(256) void ln_kernel(const u16* __restrict__ y,
                                                 const float* __restrict__ bc,
                                                 const float* __restrict__ g,
                                                 const float* __restrict__ bb,
                                                 u16* __restrict__ xc){
  const int row  = blockIdx.x*4 + (threadIdx.x >> 6);
  const int lane = threadIdx.x & 63;
  s16x8 v = *(const s16x8*)(y + (size_t)row*512 + lane*8);
  float4 c0 = ((const float4*)bc)[lane*2];
  float4 c1 = ((const float4*)bc)[lane*2+1];
  float f[8];
  f[0] = bf2f((u16)v[0]) + c0.x; f[1] = bf2f((u16)v[1]) + c0.y;
  f[2] = bf2f((u16)v[2]) + c0.z; f[3] = bf2f((u16)v[3]) + c0.w;
  f[4] = bf2f((u16)v[4]) + c1.x; f[5] = bf2f((u16)v[5]) + c1.y;
  f[6] = bf2f((u16)v[6]) + c1.z; f[7] = bf2f((u16)v[7]) + c1.w;
  float s = 0.f, s2 = 0.f;
  #pragma unroll
  for (int i=0;i<8;i++){ s += f[i]; s2 = fmaf(f[i], f[i], s2); }
  #pragma unroll
  for (int off=32; off>0; off>>=1){ s += __shfl_xor(s, off); s2 += __shfl_xor(s2, off); }
  float mean = s * (1.0f/512.0f);
  float var  = s2 * (1.0f/512.0f) - mean*mean;
  float rstd = rsqrtf(var + 1e-5f);
  float4 g0 = ((const float4*)g)[lane*2],  g1 = ((const float4*)g)[lane*2+1];
  float4 b0 = ((const float4*)bb)[lane*2], b1 = ((const float4*)bb)[lane*2+1];
  s16x8 o;
  o[0] = (short)f2bf((f[0]-mean)*rstd*g0.x + b0.x);
  o[1] = (short)f2bf((f[1]-mean)*rstd*g0.y + b0.y);
  o[2] = (short)f2bf((f[2]-mean)*rstd*g0.z + b0.z);
  o[3] = (short)f2bf((f[3]-mean)*rstd*g0.w + b0.w);
  o[4] = (short)f2bf((f[4]-mean)*rstd*g1.x + b1.x);
  o[5] = (short)f2bf((f[5]-mean)*rstd*g1.y + b1.y);
  o[6] = (short)f2bf((f[6]-mean)*rstd*g1.z + b1.z);
  o[7] = (short)f2bf((f[7]-mean)*rstd*g1.w + b1.w);
  *(s16x8*)(xc + (size_t)row*512 + lane*8) = o;
}

// ---------------- fused EMA + gate + retr ----------------
__global__ __launch_bounds__(256) void retr_fused(const u16* __restrict__ qkv,
                                                  const float* __restrict__ alph,
                                                  u16* __restrict__ retr){
  const int wid  = blockIdx.x*4 + (threadIdx.x >> 6);   // 0..4095
  const int lane = threadIdx.x & 63;
  const int c = wid & 63;
  const int h = (wid >> 6) & 7;
  const int b = wid >> 9;
  const float a  = alph[h];
  const float om = 1.0f - a;
  const int d  = h*64 + lane;
  const int t0 = c*RT;
  int w0 = t0 - RW; if (w0 < 0) w0 = 0;
  const int nw = t0 - w0;

  const u16* vp = qkv + ((size_t)(b*SS + w0))*1536 + 1024 + d;
  float vs = 0.f;
  #pragma unroll 8
  for (int i=0;i<nw;i++){
    vs = fmaf(a, bf2f(vp[(size_t)i*1536]), om*vs);
  }
  const u16* qp = qkv + ((size_t)(b*SS + t0))*1536 + d;
  u16* op = retr + ((size_t)(b*SS + t0))*512 + d;
  #pragma unroll 4
  for (int i=0;i<RT;i++){
    float q  = bf2f(qp[(size_t)i*1536]);
    float kk = bf2f(qp[(size_t)i*1536 + 512]);
    float v  = bf2f(qp[(size_t)i*1536 + 1024]);
    vs = fmaf(a, v, om*vs);
    float p = q*kk;
    #pragma unroll
    for (int off=32; off>0; off>>=1) p += __shfl_xor(p, off);
    float gate = 1.0f/(1.0f + __expf(-p*0.125f));
    op[(size_t)i*512] = f2bf(gate * vs);
  }
}

extern "C" void kernel_launch(void* const* d_in, const int* in_sizes, int n_in,
                              void* d_out, int out_size, void* d_ws, size_t ws_size,
                              hipStream_t stream) {
  const float* w    = (const float*)d_in[0];
  const float* b    = (const float*)d_in[1];
  const float* ipWr = (const float*)d_in[2];
  const float* ipWi = (const float*)d_in[3];
  const float* ipbr = (const float*)d_in[4];
  const float* ipbi = (const float*)d_in[5];
  const float* lng  = (const float*)d_in[6];
  const float* lnb  = (const float*)d_in[7];
  const float* Wqkv = (const float*)d_in[8];
  const float* la   = (const float*)d_in[9];
  const float* opWr = (const float*)d_in[10];
  const float* opWi = (const float*)d_in[11];
  float* out0 = (float*)d_out;                    // (B,S,D) real part
  float* out1 = out0 + (size_t)MM*DD;             // imag part

  char* base = (char*)d_ws;
  u16*   W1    = (u16*)  (base + 0);              // 512x1024 bf16 (k-interleaved)
  u16*   Wq    = (u16*)  (base + 1048576);        // 1536x512 bf16
  u16*   W3    = (u16*)  (base + 2621440);        // 1024x512 bf16
  float* bc    = (float*)(base + 3670016);        // 512 f32
  float* alph  = (float*)(base + 3672064);        // 8 f32
  float* tphi2 = (float*)(base + 3672128);        // 2048 f32
  u32*   X32   = (u32*)  (base + 3680384);        // M*512 u32 (packed bf16 pair)
  u16*   y     = (u16*)  (base + 37234816);       // M*512 bf16
  u16*   xc    = (u16*)  (base + 54012032);       // M*512 bf16
  u16*   qkv   = (u16*)  (base + 70789248);       // M*1536 bf16
  u16*   retr  = (u16*)X32;                       // alias: X dead after GEMM1

  prep_w1 <<<2048,256,0,stream>>>(ipWr, ipWi, W1);
  prep_wq <<<3072,256,0,stream>>>(Wqkv, Wq);
  prep_w3 <<<2048,256,0,stream>>>(opWr, opWi, W3);
  prep_misc<<<1,512,0,stream>>>(ipbr, ipbi, la, bc, alph);
  prep_tphi<<<8,256,0,stream>>>(tphi2);

  scan_h<<<dim3(16,CHK),256,0,stream>>>(w, b, tphi2, X32);

  gemm_bf16<1,2><<<dim3(4,128),256,0,stream>>>((const u16*)X32, W1, nullptr, nullptr, y, 512, 1024);
  ln_kernel<<<4096,256,0,stream>>>(y, bc, lng, lnb, xc);
  gemm_bf16<2,2><<<dim3(12,128),256,0,stream>>>(xc, Wq, nullptr, nullptr, qkv, 1536, 512);

  retr_fused<<<1024,256,0,stream>>>(qkv, alph, retr);

  gemm_bf16<3,1><<<dim3(8,128),256,0,stream>>>(retr, W3, out0, out1, nullptr, 1024, 512);
}

// Round 7
// 165.993 us; speedup vs baseline: 1.4472x; 1.0913x over previous
//
#include <hip/hip_runtime.h>
#include <math.h>

#define BB 8
#define SS 2048
#define DD 512
#define HH 8
#define MM (BB*SS)   // 16384

// scan_h chunking
#define CHK 64    // chunks over t
#define CL  32    // stored steps per chunk (CHK*CL == SS)
#define CW  48    // warm-up steps (contraction ~e^-0.87/step; mean e^-42)

// retr fused-EMA chunking
#define RT 32     // stored steps per wave
#define RW 128    // EMA warm-up steps

typedef unsigned short u16;
typedef unsigned int   u32;
typedef float f32x4 __attribute__((ext_vector_type(4)));
typedef short s16x8 __attribute__((ext_vector_type(8)));

__device__ __forceinline__ u16 f2bf(float x){
  union { float f; unsigned u; } c; c.f = x;
  unsigned r = c.u + 0x7FFF + ((c.u >> 16) & 1);
  return (u16)(r >> 16);
}
__device__ __forceinline__ float bf2f(u16 x){
  union { unsigned u; float f; } c; c.u = ((unsigned)x) << 16;
  return c.f;
}
__device__ __forceinline__ void gload16(const u16* g, u16* l){
  __builtin_amdgcn_global_load_lds(
      (const __attribute__((address_space(1))) unsigned int*)g,
      (__attribute__((address_space(3))) unsigned int*)l, 16, 0, 0);
}

// ---------------- single fused prep kernel ----------------
// id ranges: [0,524288) W1 | [524288,1310720) Wq | [1310720,1835008) W3 |
//            [1835008,1837056) tphi2 | [1837056,1837568) bc | [1837568,1837576) alph
__global__ void prep_all(const float* __restrict__ ipWr, const float* __restrict__ ipWi,
                         const float* __restrict__ Wqkv,
                         const float* __restrict__ opWr, const float* __restrict__ opWi,
                         const float* __restrict__ ipbr, const float* __restrict__ ipbi,
                         const float* __restrict__ la,
                         u16* __restrict__ W1, u16* __restrict__ Wq, u16* __restrict__ W3,
                         float* __restrict__ tphi2, float* __restrict__ bc,
                         float* __restrict__ alph){
  int id = blockIdx.x*256 + threadIdx.x;
  if (id < 524288){
    // W1[n][2d] = Wr+Wi (cos), W1[n][2d+1] = Wr-Wi (sin)
    int n = id >> 10, k = id & 1023;
    int d = k >> 1;
    float v = (k & 1) ? (ipWr[n*512+d] - ipWi[n*512+d])
                      : (ipWr[n*512+d] + ipWi[n*512+d]);
    W1[id] = f2bf(v);
  } else if (id < 1310720){
    int i = id - 524288;              // 1536*512, already [N][K]
    Wq[i] = f2bf(Wqkv[i]);
  } else if (id < 1835008){
    int i = id - 1310720;             // 1024*512
    int n = i >> 9, k = i & 511;
    W3[i] = f2bf((n < 512) ? opWr[n*512+k] : opWi[(n-512)*512+k]);
  } else if (id < 1837056){
    int t = id - 1835008;
    const float PHI_F    = 1.61803398874989484820f;
    const float TWO_PI_F = 6.28318530717958647693f;
    tphi2[t] = 2.0f * fmodf((float)t * PHI_F, TWO_PI_F);
  } else if (id < 1837568){
    int t = id - 1837056;
    bc[t] = ipbr[t] + ipbi[t];
  } else if (id < 1837576){
    int t = id - 1837568;
    alph[t] = 1.0f/(1.0f + expf(-la[t]));
  }
}

// ---------------- phase 1: h-recurrence, chunked restart ----------------
// X32[row][d] = pack(bf16(cos theta), bf16(sin theta)), row = b*S+t.
// Warm-up tracks ss = sin(theta+pi/4): cos+sin = sqrt2*sin(theta+pi/4).
// Register double-buffered loads (8 ahead) to keep ~16 loads in flight.
__global__ __launch_bounds__(256) void scan_h(const float* __restrict__ w,
                                              const float* __restrict__ bb,
                                              const float* __restrict__ tphi2,
                                              u32* __restrict__ X32){
  const int e = blockIdx.x*256 + threadIdx.x;   // 0..4095 = B*D
  const int c = blockIdx.y;                     // chunk
  const int b = e >> 9;
  const int d = e & 511;
  const float SQRT2 = 1.41421356237309504880f;
  const float PI_4  = 0.78539816339744830962f;
  const int tstart = c*CL;
  int t0 = tstart - CW; if (t0 < 0) t0 = 0;
  const int nw = tstart - t0;                   // 0, 32, or 48 (multiple of 8)

  const float* wp = w  + ((size_t)b*SS + t0)*DD + d;
  const float* bp = bb + ((size_t)b*SS + t0)*DD + d;
  const float* tp = tphi2 + t0;

  const int U = 8;
  float wv[U], bv[U], wn[U], bn[U];

  float ss = 0.f;   // sin(theta + pi/4); hr+hi = sqrt2*ss
  const int ngw = nw >> 3;
  if (ngw > 0){
    #pragma unroll
    for (int i=0;i<U;i++){ wv[i] = wp[(size_t)i*DD]; bv[i] = bp[(size_t)i*DD]; }
    for (int gg=0; gg<ngw; ++gg){
      if (gg+1 < ngw){
        const float* wnp = wp + (size_t)(gg+1)*U*DD;
        const float* bnp = bp + (size_t)(gg+1)*U*DD;
        #pragma unroll
        for (int i=0;i<U;i++){ wn[i] = wnp[(size_t)i*DD]; bn[i] = bnp[(size_t)i*DD]; }
      }
      #pragma unroll
      for (int i=0;i<U;i++){
        float rwl2 = SQRT2 * __builtin_amdgcn_rcpf(1.0f + fabsf(wv[i]));
        float cw   = fmaf(2.0f, bv[i], tp[gg*U+i]) + PI_4;
        ss = __sinf(fmaf(ss, rwl2, cw));
      }
      #pragma unroll
      for (int i=0;i<U;i++){ wv[i]=wn[i]; bv[i]=bn[i]; }
    }
  }
  float hs = SQRT2 * ss;   // = hr + hi

  const float* wq = wp + (size_t)nw*DD;
  const float* bq = bp + (size_t)nw*DD;
  const float* tq = tp + nw;
  u32* xp = X32 + (size_t)(b*SS + tstart)*512 + d;

  #pragma unroll
  for (int i=0;i<U;i++){ wv[i] = wq[(size_t)i*DD]; bv[i] = bq[(size_t)i*DD]; }
  for (int gg=0; gg<CL/U; ++gg){
    if (gg+1 < CL/U){
      const float* wnp = wq + (size_t)(gg+1)*U*DD;
      const float* bnp = bq + (size_t)(gg+1)*U*DD;
      #pragma unroll
      for (int i=0;i<U;i++){ wn[i] = wnp[(size_t)i*DD]; bn[i] = bnp[(size_t)i*DD]; }
    }
    #pragma unroll
    for (int i=0;i<U;i++){
      float rwl = __builtin_amdgcn_rcpf(1.0f + fabsf(wv[i]));
      float cc  = fmaf(2.0f, bv[i], tq[gg*U+i]);
      float theta = fmaf(hs, rwl, cc);
      float sn = __sinf(theta);
      float cs = __cosf(theta);
      hs = cs + sn;
      xp[(size_t)(gg*U+i)*512] = (u32)f2bf(cs) | ((u32)f2bf(sn) << 16);
    }
    #pragma unroll
    for (int i=0;i<U;i++){ wv[i]=wn[i]; bv[i]=bn[i]; }
  }
}

// ---------------- bf16 MFMA GEMM: C[M x N] = A[M x K] @ W[N x K]^T ----------------
// 128x128 tile, BK=32, 4 waves, 2-phase double-buffered global_load_lds staging.
// Bijective XCD swizzle; LDS slot (row,kg) holds k-chunk kg^((row>>1)&3).
// EPI: 1 = f32 split C0/C1 stride 512; 2 = bf16->C2 stride N. TAG: profiling id.
template<int TAG, int EPI>
__global__ __launch_bounds__(256) void gemm_bf16(const u16* __restrict__ A,
                                                 const u16* __restrict__ W,
                                                 float* __restrict__ C0,
                                                 float* __restrict__ C1,
                                                 u16* __restrict__ C2,
                                                 int N, int K){
  __shared__ __align__(16) u16 As[2][128*32];
  __shared__ __align__(16) u16 Bs[2][128*32];
  const int tid  = threadIdx.x;
  const int nwgx = gridDim.x;
  const int nwg  = nwgx * gridDim.y;
  const int lin  = blockIdx.y * nwgx + blockIdx.x;
  const int qq   = nwg >> 3;
  const int logi = (lin & 7) * qq + (lin >> 3);
  const int m0   = (logi / nwgx) * 128;
  const int n0   = (logi % nwgx) * 128;

  const int wave = tid >> 6;
  const int lane = tid & 63;
  const int wr   = wave >> 1, wc = wave & 1;
  const int l15  = lane & 15;
  const int g    = lane >> 4;

  const int rI   = lane >> 2;
  const int kgs  = (lane & 3) ^ ((lane >> 3) & 3);
  const int row0 = (wave*2+0)*16 + rI;
  const int row1 = (wave*2+1)*16 + rI;
  const u16* Asrc0 = A + (size_t)(m0 + row0) * K + kgs*8;
  const u16* Asrc1 = A + (size_t)(m0 + row1) * K + kgs*8;
  const u16* Bsrc0 = W + (size_t)(n0 + row0) * K + kgs*8;
  const u16* Bsrc1 = W + (size_t)(n0 + row1) * K + kgs*8;
  const int ld0 = (wave*2+0)*512;
  const int ld1 = (wave*2+1)*512;

  f32x4 acc[4][4];
  #pragma unroll
  for (int i=0;i<4;i++)
    #pragma unroll
    for (int j=0;j<4;j++) acc[i][j] = (f32x4){0.f,0.f,0.f,0.f};

#define STAGE(buf, koff) do {                      \
    gload16(Asrc0 + (koff), &As[buf][ld0]);        \
    gload16(Asrc1 + (koff), &As[buf][ld1]);        \
    gload16(Bsrc0 + (koff), &Bs[buf][ld0]);        \
    gload16(Bsrc1 + (koff), &Bs[buf][ld1]);        \
  } while(0)

#define COMPUTE(buf) do {                                            \
    s16x8 af[4], bf[4];                                              \
    _Pragma("unroll")                                                \
    for (int s=0;s<4;s++){                                           \
      int rA = wr*64 + s*16 + l15;                                   \
      af[s] = *(const s16x8*)&As[buf][rA*32 + ((g ^ ((rA>>1)&3))*8)];\
      int rB = wc*64 + s*16 + l15;                                   \
      bf[s] = *(const s16x8*)&Bs[buf][rB*32 + ((g ^ ((rB>>1)&3))*8)];\
    }                                                                \
    _Pragma("unroll")                                                \
    for (int mi=0;mi<4;mi++)                                         \
      _Pragma("unroll")                                              \
      for (int ni=0;ni<4;ni++)                                       \
        acc[mi][ni] = __builtin_amdgcn_mfma_f32_16x16x32_bf16(af[mi], bf[ni], acc[mi][ni], 0, 0, 0); \
  } while(0)

  STAGE(0, 0);
  __syncthreads();
  int cur = 0;
  for (int k0 = 32; k0 < K; k0 += 32){
    STAGE(cur^1, k0);
    COMPUTE(cur);
    __syncthreads();
    cur ^= 1;
  }
  COMPUTE(cur);

#undef STAGE
#undef COMPUTE

  #pragma unroll
  for (int mi=0;mi<4;mi++){
    #pragma unroll
    for (int j=0;j<4;j++){
      int r = m0 + wr*64 + mi*16 + g*4 + j;
      #pragma unroll
      for (int ni=0;ni<4;ni++){
        int col = n0 + wc*64 + ni*16 + l15;
        float v = acc[mi][ni][j];
        if (EPI == 1){
          if (col < 512) C0[(size_t)r*512 + col]       = v;
          else           C1[(size_t)r*512 + (col-512)] = v;
        } else {
          C2[(size_t)r*N + col] = f2bf(v);
        }
      }
    }
  }
}

// ---------------- LayerNorm: xc = LN(y + bc)*g + b  (bf16 in, bf16 out) ----------------
__global__ __launch_bounds__(256) void ln_kernel(const u16* __restrict__ y,
                                                 const float* __restrict__ bc,
                                                 const float* __restrict__ g,
                                                 const float* __restrict__ bb,
                                                 u16* __restrict__ xc){
  const int row  = blockIdx.x*4 + (threadIdx.x >> 6);
  const int lane = threadIdx.x & 63;
  s16x8 v = *(const s16x8*)(y + (size_t)row*512 + lane*8);
  float4 c0 = ((const float4*)bc)[lane*2];
  float4 c1 = ((const float4*)bc)[lane*2+1];
  float f[8];
  f[0] = bf2f((u16)v[0]) + c0.x; f[1] = bf2f((u16)v[1]) + c0.y;
  f[2] = bf2f((u16)v[2]) + c0.z; f[3] = bf2f((u16)v[3]) + c0.w;
  f[4] = bf2f((u16)v[4]) + c1.x; f[5] = bf2f((u16)v[5]) + c1.y;
  f[6] = bf2f((u16)v[6]) + c1.z; f[7] = bf2f((u16)v[7]) + c1.w;
  float s = 0.f, s2 = 0.f;
  #pragma unroll
  for (int i=0;i<8;i++){ s += f[i]; s2 = fmaf(f[i], f[i], s2); }
  #pragma unroll
  for (int off=32; off>0; off>>=1){ s += __shfl_xor(s, off); s2 += __shfl_xor(s2, off); }
  float mean = s * (1.0f/512.0f);
  float var  = s2 * (1.0f/512.0f) - mean*mean;
  float rstd = rsqrtf(var + 1e-5f);
  float4 g0 = ((const float4*)g)[lane*2],  g1 = ((const float4*)g)[lane*2+1];
  float4 b0 = ((const float4*)bb)[lane*2], b1 = ((const float4*)bb)[lane*2+1];
  s16x8 o;
  o[0] = (short)f2bf((f[0]-mean)*rstd*g0.x + b0.x);
  o[1] = (short)f2bf((f[1]-mean)*rstd*g0.y + b0.y);
  o[2] = (short)f2bf((f[2]-mean)*rstd*g0.z + b0.z);
  o[3] = (short)f2bf((f[3]-mean)*rstd*g0.w + b0.w);
  o[4] = (short)f2bf((f[4]-mean)*rstd*g1.x + b1.x);
  o[5] = (short)f2bf((f[5]-mean)*rstd*g1.y + b1.y);
  o[6] = (short)f2bf((f[6]-mean)*rstd*g1.z + b1.z);
  o[7] = (short)f2bf((f[7]-mean)*rstd*g1.w + b1.w);
  *(s16x8*)(xc + (size_t)row*512 + lane*8) = o;
}

// ---------------- fused EMA + gate + retr ----------------
__global__ __launch_bounds__(256) void retr_fused(const u16* __restrict__ qkv,
                                                  const float* __restrict__ alph,
                                                  u16* __restrict__ retr){
  const int wid  = blockIdx.x*4 + (threadIdx.x >> 6);   // 0..4095
  const int lane = threadIdx.x & 63;
  const int c = wid & 63;
  const int h = (wid >> 6) & 7;
  const int b = wid >> 9;
  const float a  = alph[h];
  const float om = 1.0f - a;
  const int d  = h*64 + lane;
  const int t0 = c*RT;
  int w0 = t0 - RW; if (w0 < 0) w0 = 0;
  const int nw = t0 - w0;                      // multiple of 32

  const u16* vp = qkv + ((size_t)(b*SS + w0))*1536 + 1024 + d;
  float vs = 0.f;
  {
    const int U = 8;
    float vv[U], vn[U];
    const int ng = nw >> 3;
    if (ng > 0){
      #pragma unroll
      for (int i=0;i<U;i++) vv[i] = bf2f(vp[(size_t)i*1536]);
      for (int gg=0; gg<ng; ++gg){
        if (gg+1 < ng){
          const u16* vnp = vp + (size_t)(gg+1)*U*1536;
          #pragma unroll
          for (int i=0;i<U;i++) vn[i] = bf2f(vnp[(size_t)i*1536]);
        }
        #pragma unroll
        for (int i=0;i<U;i++) vs = fmaf(a, vv[i], om*vs);
        #pragma unroll
        for (int i=0;i<U;i++) vv[i] = vn[i];
      }
    }
  }
  const u16* qp = qkv + ((size_t)(b*SS + t0))*1536 + d;
  u16* op = retr + ((size_t)(b*SS + t0))*512 + d;
  #pragma unroll 4
  for (int i=0;i<RT;i++){
    float q  = bf2f(qp[(size_t)i*1536]);
    float kk = bf2f(qp[(size_t)i*1536 + 512]);
    float v  = bf2f(qp[(size_t)i*1536 + 1024]);
    vs = fmaf(a, v, om*vs);
    float p = q*kk;
    #pragma unroll
    for (int off=32; off>0; off>>=1) p += __shfl_xor(p, off);
    float gate = 1.0f/(1.0f + __expf(-p*0.125f));
    op[(size_t)i*512] = f2bf(gate * vs);
  }
}

extern "C" void kernel_launch(void* const* d_in, const int* in_sizes, int n_in,
                              void* d_out, int out_size, void* d_ws, size_t ws_size,
                              hipStream_t stream) {
  const float* w    = (const float*)d_in[0];
  const float* b    = (const float*)d_in[1];
  const float* ipWr = (const float*)d_in[2];
  const float* ipWi = (const float*)d_in[3];
  const float* ipbr = (const float*)d_in[4];
  const float* ipbi = (const float*)d_in[5];
  const float* lng  = (const float*)d_in[6];
  const float* lnb  = (const float*)d_in[7];
  const float* Wqkv = (const float*)d_in[8];
  const float* la   = (const float*)d_in[9];
  const float* opWr = (const float*)d_in[10];
  const float* opWi = (const float*)d_in[11];
  float* out0 = (float*)d_out;                    // (B,S,D) real part
  float* out1 = out0 + (size_t)MM*DD;             // imag part

  char* base = (char*)d_ws;
  u16*   W1    = (u16*)  (base + 0);              // 512x1024 bf16 (k-interleaved)
  u16*   Wq    = (u16*)  (base + 1048576);        // 1536x512 bf16
  u16*   W3    = (u16*)  (base + 2621440);        // 1024x512 bf16
  float* bc    = (float*)(base + 3670016);        // 512 f32
  float* alph  = (float*)(base + 3672064);        // 8 f32
  float* tphi2 = (float*)(base + 3672128);        // 2048 f32
  u32*   X32   = (u32*)  (base + 3680384);        // M*512 u32 (packed bf16 pair)
  u16*   y     = (u16*)  (base + 37234816);       // M*512 bf16
  u16*   xc    = (u16*)  (base + 54012032);       // M*512 bf16
  u16*   qkv   = (u16*)  (base + 70789248);       // M*1536 bf16
  u16*   retr  = (u16*)X32;                       // alias: X dead after GEMM1

  prep_all<<<7179,256,0,stream>>>(ipWr, ipWi, Wqkv, opWr, opWi, ipbr, ipbi, la,
                                  W1, Wq, W3, tphi2, bc, alph);

  scan_h<<<dim3(16,CHK),256,0,stream>>>(w, b, tphi2, X32);

  gemm_bf16<1,2><<<dim3(4,128),256,0,stream>>>((const u16*)X32, W1, nullptr, nullptr, y, 512, 1024);
  ln_kernel<<<4096,256,0,stream>>>(y, bc, lng, lnb, xc);
  gemm_bf16<2,2><<<dim3(12,128),256,0,stream>>>(xc, Wq, nullptr, nullptr, qkv, 1536, 512);

  retr_fused<<<1024,256,0,stream>>>(qkv, alph, retr);

  gemm_bf16<3,1><<<dim3(8,128),256,0,stream>>>(retr, W3, out0, out1, nullptr, 1024, 512);
}

// Round 8
// 159.187 us; speedup vs baseline: 1.5090x; 1.0428x over previous
//
#include <hip/hip_runtime.h>
#include <math.h>

#define BB 8
#define SS 2048
#define DD 512
#define HH 8
#define MM (BB*SS)   // 16384

// scan_h chunking
#define CHK 128   // chunks over t
#define CL  16    // stored steps per chunk (CHK*CL == SS)
#define CW  48    // warm-up steps (contraction ~e^-0.87/step; mean e^-42)

// retr fused-EMA chunking
#define RT 32     // stored steps per wave
#define RW 128    // EMA warm-up steps

typedef unsigned short u16;
typedef unsigned int   u32;
typedef float f32x4 __attribute__((ext_vector_type(4)));
typedef short s16x8 __attribute__((ext_vector_type(8)));

__device__ __forceinline__ u16 f2bf(float x){
  union { float f; unsigned u; } c; c.f = x;
  unsigned r = c.u + 0x7FFF + ((c.u >> 16) & 1);
  return (u16)(r >> 16);
}
__device__ __forceinline__ float bf2f(u16 x){
  union { unsigned u; float f; } c; c.u = ((unsigned)x) << 16;
  return c.f;
}
__device__ __forceinline__ void gload16(const u16* g, u16* l){
  __builtin_amdgcn_global_load_lds(
      (const __attribute__((address_space(1))) unsigned int*)g,
      (__attribute__((address_space(3))) unsigned int*)l, 16, 0, 0);
}

// ---------------- single fused prep kernel ----------------
__global__ void prep_all(const float* __restrict__ ipWr, const float* __restrict__ ipWi,
                         const float* __restrict__ Wqkv,
                         const float* __restrict__ opWr, const float* __restrict__ opWi,
                         const float* __restrict__ ipbr, const float* __restrict__ ipbi,
                         const float* __restrict__ la,
                         u16* __restrict__ W1, u16* __restrict__ Wq, u16* __restrict__ W3,
                         float* __restrict__ tphi2, float* __restrict__ bc,
                         float* __restrict__ alph){
  int id = blockIdx.x*256 + threadIdx.x;
  if (id < 524288){
    // W1[n][2d] = Wr+Wi (cos), W1[n][2d+1] = Wr-Wi (sin)
    int n = id >> 10, k = id & 1023;
    int d = k >> 1;
    float v = (k & 1) ? (ipWr[n*512+d] - ipWi[n*512+d])
                      : (ipWr[n*512+d] + ipWi[n*512+d]);
    W1[id] = f2bf(v);
  } else if (id < 1310720){
    int i = id - 524288;              // 1536*512, already [N][K]
    Wq[i] = f2bf(Wqkv[i]);
  } else if (id < 1835008){
    int i = id - 1310720;             // 1024*512
    int n = i >> 9, k = i & 511;
    W3[i] = f2bf((n < 512) ? opWr[n*512+k] : opWi[(n-512)*512+k]);
  } else if (id < 1837056){
    int t = id - 1835008;
    const float PHI_F    = 1.61803398874989484820f;
    const float TWO_PI_F = 6.28318530717958647693f;
    tphi2[t] = 2.0f * fmodf((float)t * PHI_F, TWO_PI_F);
  } else if (id < 1837568){
    int t = id - 1837056;
    bc[t] = ipbr[t] + ipbi[t];
  } else if (id < 1837576){
    int t = id - 1837568;
    alph[t] = 1.0f/(1.0f + expf(-la[t]));
  }
}

// ---------------- phase 1: h-recurrence, chunked restart ----------------
// X32[row][d] = pack(bf16(cos), bf16(sin)); warm-up single-trans recurrence.
__global__ __launch_bounds__(256) void scan_h(const float* __restrict__ w,
                                              const float* __restrict__ bb,
                                              const float* __restrict__ tphi2,
                                              u32* __restrict__ X32){
  const int e = blockIdx.x*256 + threadIdx.x;   // 0..4095 = B*D
  const int c = blockIdx.y;                     // chunk
  const int b = e >> 9;
  const int d = e & 511;
  const float SQRT2 = 1.41421356237309504880f;
  const float PI_4  = 0.78539816339744830962f;
  const int tstart = c*CL;
  int t0 = tstart - CW; if (t0 < 0) t0 = 0;
  const int nw = tstart - t0;                   // 0,16,32,48 (multiple of 8)

  const float* wp = w  + ((size_t)b*SS + t0)*DD + d;
  const float* bp = bb + ((size_t)b*SS + t0)*DD + d;
  const float* tp = tphi2 + t0;

  const int U = 8;
  float wv[U], bv[U], wn[U], bn[U];

  float ss = 0.f;   // sin(theta + pi/4); hr+hi = sqrt2*ss
  const int ngw = nw >> 3;
  if (ngw > 0){
    #pragma unroll
    for (int i=0;i<U;i++){ wv[i] = wp[(size_t)i*DD]; bv[i] = bp[(size_t)i*DD]; }
    for (int gg=0; gg<ngw; ++gg){
      if (gg+1 < ngw){
        const float* wnp = wp + (size_t)(gg+1)*U*DD;
        const float* bnp = bp + (size_t)(gg+1)*U*DD;
        #pragma unroll
        for (int i=0;i<U;i++){ wn[i] = wnp[(size_t)i*DD]; bn[i] = bnp[(size_t)i*DD]; }
      }
      #pragma unroll
      for (int i=0;i<U;i++){
        float rwl2 = SQRT2 * __builtin_amdgcn_rcpf(1.0f + fabsf(wv[i]));
        float cw   = fmaf(2.0f, bv[i], tp[gg*U+i]) + PI_4;
        ss = __sinf(fmaf(ss, rwl2, cw));
      }
      #pragma unroll
      for (int i=0;i<U;i++){ wv[i]=wn[i]; bv[i]=bn[i]; }
    }
  }
  float hs = SQRT2 * ss;   // = hr + hi

  const float* wq = wp + (size_t)nw*DD;
  const float* bq = bp + (size_t)nw*DD;
  const float* tq = tp + nw;
  u32* xp = X32 + (size_t)(b*SS + tstart)*512 + d;

  #pragma unroll
  for (int i=0;i<U;i++){ wv[i] = wq[(size_t)i*DD]; bv[i] = bq[(size_t)i*DD]; }
  for (int gg=0; gg<CL/U; ++gg){
    if (gg+1 < CL/U){
      const float* wnp = wq + (size_t)(gg+1)*U*DD;
      const float* bnp = bq + (size_t)(gg+1)*U*DD;
      #pragma unroll
      for (int i=0;i<U;i++){ wn[i] = wnp[(size_t)i*DD]; bn[i] = bnp[(size_t)i*DD]; }
    }
    #pragma unroll
    for (int i=0;i<U;i++){
      float rwl = __builtin_amdgcn_rcpf(1.0f + fabsf(wv[i]));
      float cc  = fmaf(2.0f, bv[i], tq[gg*U+i]);
      float theta = fmaf(hs, rwl, cc);
      float sn = __sinf(theta);
      float cs = __cosf(theta);
      hs = cs + sn;
      xp[(size_t)(gg*U+i)*512] = (u32)f2bf(cs) | ((u32)f2bf(sn) << 16);
    }
    #pragma unroll
    for (int i=0;i<U;i++){ wv[i]=wn[i]; bv[i]=bn[i]; }
  }
}

// ---------------- bf16 MFMA GEMM: C[M x N] = A[M x K] @ W[N x K]^T ----------------
// 128x128 tile, BK=32, 4 waves. 3-deep counted-vmcnt pipeline (AITER pattern):
// stage tile t+2, s_waitcnt vmcnt(8) (tile t landed, t+1/t+2 stay in flight),
// raw s_barrier (no drain), compute, barrier. Bijective XCD swizzle.
// LDS slot (row,kg) holds k-chunk kg^((row>>1)&3); read applies same XOR.
// EPI: 1 = f32 split C0/C1 stride 512; 2 = bf16->C2 stride N.
template<int TAG, int EPI>
__global__ __launch_bounds__(256) void gemm_bf16(const u16* __restrict__ A,
                                                 const u16* __restrict__ W,
                                                 float* __restrict__ C0,
                                                 float* __restrict__ C1,
                                                 u16* __restrict__ C2,
                                                 int N, int K){
  __shared__ __align__(16) u16 As[3][128*32];
  __shared__ __align__(16) u16 Bs[3][128*32];
  const int tid  = threadIdx.x;
  const int nwgx = gridDim.x;
  const int nwg  = nwgx * gridDim.y;
  const int lin  = blockIdx.y * nwgx + blockIdx.x;
  const int qq   = nwg >> 3;
  const int logi = (lin & 7) * qq + (lin >> 3);
  const int m0   = (logi / nwgx) * 128;
  const int n0   = (logi % nwgx) * 128;

  const int wave = tid >> 6;
  const int lane = tid & 63;
  const int wr   = wave >> 1, wc = wave & 1;
  const int l15  = lane & 15;
  const int g    = lane >> 4;

  const int rI   = lane >> 2;
  const int kgs  = (lane & 3) ^ ((lane >> 3) & 3);
  const int row0 = (wave*2+0)*16 + rI;
  const int row1 = (wave*2+1)*16 + rI;
  const u16* Asrc0 = A + (size_t)(m0 + row0) * K + kgs*8;
  const u16* Asrc1 = A + (size_t)(m0 + row1) * K + kgs*8;
  const u16* Bsrc0 = W + (size_t)(n0 + row0) * K + kgs*8;
  const u16* Bsrc1 = W + (size_t)(n0 + row1) * K + kgs*8;
  const int ld0 = (wave*2+0)*512;
  const int ld1 = (wave*2+1)*512;

  f32x4 acc[4][4];
  #pragma unroll
  for (int i=0;i<4;i++)
    #pragma unroll
    for (int j=0;j<4;j++) acc[i][j] = (f32x4){0.f,0.f,0.f,0.f};

#define STAGE(buf, koff) do {                      \
    gload16(Asrc0 + (koff), &As[buf][ld0]);        \
    gload16(Asrc1 + (koff), &As[buf][ld1]);        \
    gload16(Bsrc0 + (koff), &Bs[buf][ld0]);        \
    gload16(Bsrc1 + (koff), &Bs[buf][ld1]);        \
  } while(0)

#define COMPUTE(buf) do {                                            \
    s16x8 af[4], bf[4];                                              \
    _Pragma("unroll")                                                \
    for (int s=0;s<4;s++){                                           \
      int rA = wr*64 + s*16 + l15;                                   \
      af[s] = *(const s16x8*)&As[buf][rA*32 + ((g ^ ((rA>>1)&3))*8)];\
      int rB = wc*64 + s*16 + l15;                                   \
      bf[s] = *(const s16x8*)&Bs[buf][rB*32 + ((g ^ ((rB>>1)&3))*8)];\
    }                                                                \
    _Pragma("unroll")                                                \
    for (int mi=0;mi<4;mi++)                                         \
      _Pragma("unroll")                                              \
      for (int ni=0;ni<4;ni++)                                       \
        acc[mi][ni] = __builtin_amdgcn_mfma_f32_16x16x32_bf16(af[mi], bf[ni], acc[mi][ni], 0, 0, 0); \
  } while(0)

  const int nt = K >> 5;          // K/32 tiles (>=16 for all our shapes)
  STAGE(0, 0);
  STAGE(1, 32);
  int cur = 0;                    // buffer holding tile t
  for (int t = 0; t < nt; ++t){
    if (t+2 < nt){
      int nb = cur+2; if (nb >= 3) nb -= 3;
      STAGE(nb, (t+2)*32);
      asm volatile("s_waitcnt vmcnt(8)" ::: "memory");   // tile t landed
    } else if (t+1 < nt){
      asm volatile("s_waitcnt vmcnt(4)" ::: "memory");
    } else {
      asm volatile("s_waitcnt vmcnt(0)" ::: "memory");
    }
    __builtin_amdgcn_s_barrier();      // all waves' tile-t DMAs landed
    COMPUTE(cur);
    asm volatile("" ::: "memory");
    __builtin_amdgcn_s_barrier();      // all waves done reading buf before re-stage
    cur = (cur==2) ? 0 : cur+1;
  }

#undef STAGE
#undef COMPUTE

  #pragma unroll
  for (int mi=0;mi<4;mi++){
    #pragma unroll
    for (int j=0;j<4;j++){
      int r = m0 + wr*64 + mi*16 + g*4 + j;
      #pragma unroll
      for (int ni=0;ni<4;ni++){
        int col = n0 + wc*64 + ni*16 + l15;
        float v = acc[mi][ni][j];
        if (EPI == 1){
          if (col < 512) C0[(size_t)r*512 + col]       = v;
          else           C1[(size_t)r*512 + (col-512)] = v;
        } else {
          C2[(size_t)r*N + col] = f2bf(v);
        }
      }
    }
  }
}

// ---------------- LayerNorm: xc = LN(y + bc)*g + b  (bf16 in, bf16 out) ----------------
__global__ __launch_bounds__(256) void ln_kernel(const u16* __restrict__ y,
                                                 const float* __restrict__ bc,
                                                 const float* __restrict__ g,
                                                 const float* __restrict__ bb,
                                                 u16* __restrict__ xc){
  const int row  = blockIdx.x*4 + (threadIdx.x >> 6);
  const int lane = threadIdx.x & 63;
  s16x8 v = *(const s16x8*)(y + (size_t)row*512 + lane*8);
  float4 c0 = ((const float4*)bc)[lane*2];
  float4 c1 = ((const float4*)bc)[lane*2+1];
  float f[8];
  f[0] = bf2f((u16)v[0]) + c0.x; f[1] = bf2f((u16)v[1]) + c0.y;
  f[2] = bf2f((u16)v[2]) + c0.z; f[3] = bf2f((u16)v[3]) + c0.w;
  f[4] = bf2f((u16)v[4]) + c1.x; f[5] = bf2f((u16)v[5]) + c1.y;
  f[6] = bf2f((u16)v[6]) + c1.z; f[7] = bf2f((u16)v[7]) + c1.w;
  float s = 0.f, s2 = 0.f;
  #pragma unroll
  for (int i=0;i<8;i++){ s += f[i]; s2 = fmaf(f[i], f[i], s2); }
  #pragma unroll
  for (int off=32; off>0; off>>=1){ s += __shfl_xor(s, off); s2 += __shfl_xor(s2, off); }
  float mean = s * (1.0f/512.0f);
  float var  = s2 * (1.0f/512.0f) - mean*mean;
  float rstd = rsqrtf(var + 1e-5f);
  float4 g0 = ((const float4*)g)[lane*2],  g1 = ((const float4*)g)[lane*2+1];
  float4 b0 = ((const float4*)bb)[lane*2], b1 = ((const float4*)bb)[lane*2+1];
  s16x8 o;
  o[0] = (short)f2bf((f[0]-mean)*rstd*g0.x + b0.x);
  o[1] = (short)f2bf((f[1]-mean)*rstd*g0.y + b0.y);
  o[2] = (short)f2bf((f[2]-mean)*rstd*g0.z + b0.z);
  o[3] = (short)f2bf((f[3]-mean)*rstd*g0.w + b0.w);
  o[4] = (short)f2bf((f[4]-mean)*rstd*g1.x + b1.x);
  o[5] = (short)f2bf((f[5]-mean)*rstd*g1.y + b1.y);
  o[6] = (short)f2bf((f[6]-mean)*rstd*g1.z + b1.z);
  o[7] = (short)f2bf((f[7]-mean)*rstd*g1.w + b1.w);
  *(s16x8*)(xc + (size_t)row*512 + lane*8) = o;
}

// ---------------- fused EMA + gate + retr ----------------
__global__ __launch_bounds__(256) void retr_fused(const u16* __restrict__ qkv,
                                                  const float* __restrict__ alph,
                                                  u16* __restrict__ retr){
  const int wid  = blockIdx.x*4 + (threadIdx.x >> 6);   // 0..4095
  const int lane = threadIdx.x & 63;
  const int c = wid & 63;
  const int h = (wid >> 6) & 7;
  const int b = wid >> 9;
  const float a  = alph[h];
  const float om = 1.0f - a;
  const int d  = h*64 + lane;
  const int t0 = c*RT;
  int w0 = t0 - RW; if (w0 < 0) w0 = 0;
  const int nw = t0 - w0;                      // multiple of 32

  const u16* vp = qkv + ((size_t)(b*SS + w0))*1536 + 1024 + d;
  float vs = 0.f;
  {
    const int U = 8;
    float vv[U], vn[U];
    const int ng = nw >> 3;
    if (ng > 0){
      #pragma unroll
      for (int i=0;i<U;i++) vv[i] = bf2f(vp[(size_t)i*1536]);
      for (int gg=0; gg<ng; ++gg){
        if (gg+1 < ng){
          const u16* vnp = vp + (size_t)(gg+1)*U*1536;
          #pragma unroll
          for (int i=0;i<U;i++) vn[i] = bf2f(vnp[(size_t)i*1536]);
        }
        #pragma unroll
        for (int i=0;i<U;i++) vs = fmaf(a, vv[i], om*vs);
        #pragma unroll
        for (int i=0;i<U;i++) vv[i] = vn[i];
      }
    }
  }
  const u16* qp = qkv + ((size_t)(b*SS + t0))*1536 + d;
  u16* op = retr + ((size_t)(b*SS + t0))*512 + d;
  #pragma unroll 4
  for (int i=0;i<RT;i++){
    float q  = bf2f(qp[(size_t)i*1536]);
    float kk = bf2f(qp[(size_t)i*1536 + 512]);
    float v  = bf2f(qp[(size_t)i*1536 + 1024]);
    vs = fmaf(a, v, om*vs);
    float p = q*kk;
    #pragma unroll
    for (int off=32; off>0; off>>=1) p += __shfl_xor(p, off);
    float gate = 1.0f/(1.0f + __expf(-p*0.125f));
    op[(size_t)i*512] = f2bf(gate * vs);
  }
}

extern "C" void kernel_launch(void* const* d_in, const int* in_sizes, int n_in,
                              void* d_out, int out_size, void* d_ws, size_t ws_size,
                              hipStream_t stream) {
  const float* w    = (const float*)d_in[0];
  const float* b    = (const float*)d_in[1];
  const float* ipWr = (const float*)d_in[2];
  const float* ipWi = (const float*)d_in[3];
  const float* ipbr = (const float*)d_in[4];
  const float* ipbi = (const float*)d_in[5];
  const float* lng  = (const float*)d_in[6];
  const float* lnb  = (const float*)d_in[7];
  const float* Wqkv = (const float*)d_in[8];
  const float* la   = (const float*)d_in[9];
  const float* opWr = (const float*)d_in[10];
  const float* opWi = (const float*)d_in[11];
  float* out0 = (float*)d_out;                    // (B,S,D) real part
  float* out1 = out0 + (size_t)MM*DD;             // imag part

  char* base = (char*)d_ws;
  u16*   W1    = (u16*)  (base + 0);              // 512x1024 bf16 (k-interleaved)
  u16*   Wq    = (u16*)  (base + 1048576);        // 1536x512 bf16
  u16*   W3    = (u16*)  (base + 2621440);        // 1024x512 bf16
  float* bc    = (float*)(base + 3670016);        // 512 f32
  float* alph  = (float*)(base + 3672064);        // 8 f32
  float* tphi2 = (float*)(base + 3672128);        // 2048 f32
  u32*   X32   = (u32*)  (base + 3680384);        // M*512 u32 (packed bf16 pair)
  u16*   y     = (u16*)  (base + 37234816);       // M*512 bf16
  u16*   xc    = (u16*)  (base + 54012032);       // M*512 bf16
  u16*   qkv   = (u16*)  (base + 70789248);       // M*1536 bf16
  u16*   retr  = (u16*)X32;                       // alias: X dead after GEMM1

  prep_all<<<7179,256,0,stream>>>(ipWr, ipWi, Wqkv, opWr, opWi, ipbr, ipbi, la,
                                  W1, Wq, W3, tphi2, bc, alph);

  scan_h<<<dim3(16,CHK),256,0,stream>>>(w, b, tphi2, X32);

  gemm_bf16<1,2><<<dim3(4,128),256,0,stream>>>((const u16*)X32, W1, nullptr, nullptr, y, 512, 1024);
  ln_kernel<<<4096,256,0,stream>>>(y, bc, lng, lnb, xc);
  gemm_bf16<2,2><<<dim3(12,128),256,0,stream>>>(xc, Wq, nullptr, nullptr, qkv, 1536, 512);

  retr_fused<<<1024,256,0,stream>>>(qkv, alph, retr);

  gemm_bf16<3,1><<<dim3(8,128),256,0,stream>>>(retr, W3, out0, out1, nullptr, 1024, 512);
}